// Round 8
// baseline (599.635 us; speedup 1.0000x reference)
//
#include <hip/hip_runtime.h>
#include <cstddef>

// ---------------------------------------------------------------------------
// RQ-VAE forward, bf16-MFMA pipeline.
//   prep:  x -> bf16; weights -> Wt bf16 [N][K]; codebooks -> bf16 + norms
//   G1: H1 = gelu(xbf @ eW1 + eb1)                                    -> bf16
//   G2: Z  = H1 @ eW2 + eb2                                           -> f32
//   VQ: 3 stages (reg residual, LDS-staged swizzled codebook tiles)
//   G3: H2 = gelu(ZQ @ dW1 + db1)                                     -> bf16
//   G4: recon = mean((H2 @ dW2 + db2 - xbf)^2)   (loss-only epilogue)
// GEMM template: 256x128 tile, BK=64, 512 thr (8 waves, 4Mx2N), TRIPLE-
// buffered LDS + counted vmcnt(6) pipeline, one raw s_barrier per K-tile.
// ---------------------------------------------------------------------------

typedef __attribute__((ext_vector_type(8))) __bf16 bf16x8;
typedef __attribute__((ext_vector_type(4))) float f32x4;
typedef unsigned short u16;

__device__ __forceinline__ u16 f2bf(float f) {
    unsigned u = __float_as_uint(f);
    u += 0x7fffu + ((u >> 16) & 1u);      // round-to-nearest-even
    return (u16)(u >> 16);
}
__device__ __forceinline__ float bf2f(u16 b) {
    return __uint_as_float((unsigned)b << 16);
}
__device__ __forceinline__ float gelu_exact(float v) {
    return 0.5f * v * (1.0f + erff(v * 0.7071067811865475f));
}
__device__ __forceinline__ void gload16(const void* g, void* l) {
    __builtin_amdgcn_global_load_lds(
        (const __attribute__((address_space(1))) void*)g,
        (__attribute__((address_space(3))) void*)l, 16, 0, 0);
}
__device__ __forceinline__ f32x4 mfma_bf16(bf16x8 a, bf16x8 b, f32x4 c) {
    return __builtin_amdgcn_mfma_f32_16x16x32_bf16(a, b, c, 0, 0, 0);
}

// ---------------------------------------------------------------------------
// x -> bf16 (vectorized cast, grid-stride)
__global__ __launch_bounds__(256)
void prep_x(const float* __restrict__ x, u16* __restrict__ xbf)
{
    const size_t total = (size_t)65536 * 1024;
    const size_t step  = (size_t)gridDim.x * 256 * 8;
    for (size_t i = ((size_t)blockIdx.x * 256 + threadIdx.x) * 8; i < total; i += step) {
        float4 v0 = *(const float4*)&x[i];
        float4 v1 = *(const float4*)&x[i + 4];
        uint4 o;
        o.x = (unsigned)f2bf(v0.x) | ((unsigned)f2bf(v0.y) << 16);
        o.y = (unsigned)f2bf(v0.z) | ((unsigned)f2bf(v0.w) << 16);
        o.z = (unsigned)f2bf(v1.x) | ((unsigned)f2bf(v1.y) << 16);
        o.w = (unsigned)f2bf(v1.z) | ((unsigned)f2bf(v1.w) << 16);
        *(uint4*)&xbf[i] = o;
    }
}

// ---------------------------------------------------------------------------
// prep: transpose+cast the 4 weights to bf16 [N][K]
__global__ __launch_bounds__(256)
void prep_weights(const float* __restrict__ eW1, const float* __restrict__ eW2,
                  const float* __restrict__ dW1, const float* __restrict__ dW2,
                  u16* __restrict__ eW1t, u16* __restrict__ eW2t,
                  u16* __restrict__ dW1t, u16* __restrict__ dW2t)
{
    const int b = blockIdx.x, t = threadIdx.x;
    if (b < 2048) {                    // eW1 [1024][512] -> [512][1024]
        int e = b * 256 + t;
        int n = e >> 10, k = e & 1023;
        eW1t[e] = f2bf(eW1[(size_t)k * 512 + n]);
    } else if (b < 2560) {             // eW2 [512][256] -> [256][512]
        int e = (b - 2048) * 256 + t;
        int n = e >> 9, k = e & 511;
        eW2t[e] = f2bf(eW2[(size_t)k * 256 + n]);
    } else if (b < 3072) {             // dW1 [256][512] -> [512][256]
        int e = (b - 2560) * 256 + t;
        int n = e >> 8, k = e & 255;
        dW1t[e] = f2bf(dW1[(size_t)k * 512 + n]);
    } else {                           // dW2 [512][1024] -> [1024][512]
        int e = (b - 3072) * 256 + t;
        int n = e >> 9, k = e & 511;
        dW2t[e] = f2bf(dW2[(size_t)k * 1024 + n]);
    }
}

// codebooks: bf16 cast (contiguous [1792][256]) + f32 squared norms
__global__ __launch_bounds__(256)
void cb_prep(const float* __restrict__ C0, const float* __restrict__ C1,
             const float* __restrict__ C2, u16* __restrict__ Cbf,
             float* __restrict__ cnorm)
{
    __shared__ float red[256];
    const int code = blockIdx.x, t = threadIdx.x;
    const float* C;
    int local;
    if (code < 1024)      { C = C0; local = code; }
    else if (code < 1536) { C = C1; local = code - 1024; }
    else                  { C = C2; local = code - 1536; }
    const float v = C[(size_t)local * 256 + t];
    Cbf[(size_t)code * 256 + t] = f2bf(v);
    red[t] = v * v;
    __syncthreads();
    for (int s = 128; s; s >>= 1) { if (t < s) red[t] += red[t + s]; __syncthreads(); }
    if (t == 0) cnorm[code] = red[0];
}

// ---------------------------------------------------------------------------
// MFMA GEMM v2: C = A[M,K] @ Bt[N,K]^T.
// 256x128 tile, BK=64, 512 threads = 8 waves (4Mx2N), wave tile 64x64.
// Triple-buffered LDS (3 x 48 KB = 144 KB) + counted-vmcnt pipeline:
//   per K-tile: vmcnt(6) -> s_barrier -> issue stage(t+2) -> ds_read+MFMA.
// Steady-state wait is vmcnt(6) (tile t+1's 6 loads stay in flight); the
// buffer written at step t is the one whose reads finished at step t-1,
// and the issue sits after the barrier that closes those reads.
// LDS rows are 128 B with chunk-XOR (R&7) swizzle, applied on the pre-
// swizzled GLOBAL source (gload_lds dest linear) and on the ds_read side.
// EPI: 0 = gelu -> bf16 store, 1 = plain -> f32 store, 2 = sq-err loss vs Xbf
template <int EPI>
__global__ __launch_bounds__(512, 2)
void gemm_mfma(const u16* __restrict__ A, const u16* __restrict__ Bt,
               const float* __restrict__ bias, u16* __restrict__ Obf,
               float* __restrict__ Of, const u16* __restrict__ Xbf,
               float* __restrict__ lossOut, int N, int K, int ntn,
               float lossScale)
{
    __shared__ __align__(16) u16 As[3][256 * 64];   // 3 x 32 KB
    __shared__ __align__(16) u16 Bs[3][128 * 64];   // 3 x 16 KB

    const int nwg = gridDim.x;
    const int bid = blockIdx.x;
    const int wg  = (bid & 7) * (nwg >> 3) + (bid >> 3);   // XCD-chunked swizzle
    const int brow = (wg / ntn) * 256;
    const int bcol = (wg % ntn) * 128;

    const int t    = threadIdx.x;
    const int lane = t & 63;
    const int wid  = t >> 6;
    const int wrow = (wid & 3) * 64;     // 4 M-groups
    const int wcol = (wid >> 2) * 64;    // 2 N-groups
    const int lrow = lane & 15, g = lane >> 4;

    const int nt = K >> 6;   // K-tiles of 64

    f32x4 acc[4][4];
#pragma unroll
    for (int m = 0; m < 4; ++m)
#pragma unroll
        for (int n = 0; n < 4; ++n) acc[m][n] = (f32x4)0.f;

    // stage K-tile kt into buffer buf: A 4 loads + B 2 loads per thread.
    // dest linear; source 16B-chunk pre-swizzled by ch ^= row&7.
    auto stage = [&](int kt, int buf) {
#pragma unroll
        for (int it = 0; it < 4; ++it) {
            const int d   = (it * 512 + t) * 16;
            const int row = d >> 7;                // 0..255
            const int cs  = ((d >> 4) & 7) ^ (row & 7);
            gload16(&A[(size_t)(brow + row) * K + kt * 64 + cs * 8],
                    (char*)&As[buf][0] + d);
        }
#pragma unroll
        for (int it = 0; it < 2; ++it) {
            const int d   = (it * 512 + t) * 16;
            const int row = d >> 7;                // 0..127
            const int cs  = ((d >> 4) & 7) ^ (row & 7);
            gload16(&Bt[(size_t)(bcol + row) * K + kt * 64 + cs * 8],
                    (char*)&Bs[buf][0] + d);
        }
    };

    // prologue: two K-tiles in flight
    stage(0, 0);
    stage(1, 1);

    for (int kt = 0; kt < nt; ++kt) {
        if (kt < nt - 1) {
            asm volatile("s_waitcnt vmcnt(6)" ::: "memory");
        } else {
            asm volatile("s_waitcnt vmcnt(0)" ::: "memory");
        }
        __builtin_amdgcn_s_barrier();
        if (kt + 2 < nt) stage(kt + 2, (kt + 2) % 3);

        const int buf = kt % 3;
        const char* Ab = (const char*)&As[buf][0];
        const char* Bb = (const char*)&Bs[buf][0];

        __builtin_amdgcn_s_setprio(1);
#pragma unroll
        for (int ks = 0; ks < 2; ++ks) {
            bf16x8 a[4], b[4];
#pragma unroll
            for (int m = 0; m < 4; ++m) {
                const int R = wrow + m * 16 + lrow;
                a[m] = *(const bf16x8*)(Ab + R * 128 + (((ks * 4 + g) ^ (R & 7)) << 4));
            }
#pragma unroll
            for (int n = 0; n < 4; ++n) {
                const int R = wcol + n * 16 + lrow;
                b[n] = *(const bf16x8*)(Bb + R * 128 + (((ks * 4 + g) ^ (R & 7)) << 4));
            }
#pragma unroll
            for (int m = 0; m < 4; ++m)
#pragma unroll
                for (int n = 0; n < 4; ++n)
                    acc[m][n] = mfma_bf16(a[m], b[n], acc[m][n]);
        }
        __builtin_amdgcn_s_setprio(0);
    }

    // ---- epilogue ----
    int   colN[4];
    float bn[4];
#pragma unroll
    for (int n = 0; n < 4; ++n) {
        colN[n] = bcol + wcol + n * 16 + lrow;
        bn[n]   = bias[colN[n]];
    }

    if (EPI == 0) {
#pragma unroll
        for (int m = 0; m < 4; ++m) {
            const int rowb = brow + wrow + m * 16 + (lane >> 4) * 4;
#pragma unroll
            for (int n = 0; n < 4; ++n)
#pragma unroll
                for (int j = 0; j < 4; ++j)
                    Obf[(size_t)(rowb + j) * N + colN[n]] =
                        f2bf(gelu_exact(acc[m][n][j] + bn[n]));
        }
    } else if (EPI == 1) {
#pragma unroll
        for (int m = 0; m < 4; ++m) {
            const int rowb = brow + wrow + m * 16 + (lane >> 4) * 4;
#pragma unroll
            for (int n = 0; n < 4; ++n)
#pragma unroll
                for (int j = 0; j < 4; ++j)
                    Of[(size_t)(rowb + j) * N + colN[n]] = acc[m][n][j] + bn[n];
        }
    } else {
        float partial = 0.f;
#pragma unroll
        for (int m = 0; m < 4; ++m) {
            const int rowb = brow + wrow + m * 16 + (lane >> 4) * 4;
#pragma unroll
            for (int n = 0; n < 4; ++n)
#pragma unroll
                for (int j = 0; j < 4; ++j) {
                    const float o = acc[m][n][j] + bn[n];
                    const float d = o - bf2f(Xbf[(size_t)(rowb + j) * N + colN[n]]);
                    partial = fmaf(d, d, partial);
                }
        }
        __syncthreads();                 // all waves out of the K-loop (LDS reuse)
        float* red = (float*)&As[0][0];
        red[t] = partial;
        __syncthreads();
        for (int s = 256; s; s >>= 1) { if (t < s) red[t] += red[t + s]; __syncthreads(); }
        if (t == 0) atomicAdd(lossOut, red[0] * lossScale);
    }
}

// ---------------------------------------------------------------------------
// VQ v5: 512 threads, 64 rows/block. Thread (col = t&255, rh = t>>8) owns
// rows rh*32..rh*32+31 of its column -> R[32] f32 in regs.
// 8 waves = 4 row-groups x 2 code-halves. Per stage:
//   - bf16 mirror of R into LDS; wave loads its 16-row A-frags to regs
//   - codebook tiles (32 codes x 256 k = 16KB) staged via global_load_lds,
//     double-buffered; XOR swizzle (row&7)<<4 on pre-swizzled global source,
//     mirrored on the ds_read side (both-sides rule)
//   - per tile: 8 ds_read_b128 + 8 MFMA per wave, one barrier per tile
//   - wave argmin over 16 code-lanes, cross-half combine in LDS
//   - f32 residual update + commit loss (shfl + 8-slot reduce)
// Final: ZQ = C0[i0]+C1[i1]+C2[i2] (no Z re-read).
__global__ __launch_bounds__(512, 4)
void vq_mfma(const float* __restrict__ Z, const u16* __restrict__ Cbf,
             const float* __restrict__ cnorm,
             const float* __restrict__ C0, const float* __restrict__ C1,
             const float* __restrict__ C2,
             u16* __restrict__ ZQ, float* __restrict__ lossOut)
{
    __shared__ __align__(16) u16 Rb[64][264];      // 33.8 KB residual mirror
    __shared__ __align__(16) u16 Cs[2][32 * 256];  // 2 x 16 KB code tiles
    __shared__ float redv[64][2];
    __shared__ int   redi[64][2];
    __shared__ int   idxs[3][64];
    __shared__ float lred[8];

    const int t    = threadIdx.x;
    const int lane = t & 63;
    const int wid  = t >> 6;           // 0..7
    const int rg   = wid & 3;          // row group (16 rows)
    const int cg   = wid >> 2;         // code half
    const int lrow = lane & 15, g = lane >> 4;
    const int col  = t & 255;          // owned column
    const int rh   = t >> 8;           // row half (32 rows)
    const int brow = blockIdx.x * 64;

    float R[32];
#pragma unroll
    for (int r = 0; r < 32; ++r)
        R[r] = Z[(size_t)(brow + rh * 32 + r) * 256 + col];

    const float* Cf[3]  = {C0, C1, C2};
    const int ncodes[3] = {1024, 512, 256};
    const int coff[3]   = {0, 1024, 1536};
    const float lscale  = 1.25f / (65536.0f * 256.0f);

    for (int stage = 0; stage < 3; ++stage) {
        const u16*   Cb  = Cbf + (size_t)coff[stage] * 256;
        const float* cns = cnorm + coff[stage];
        const int ntile  = ncodes[stage] >> 5;

        // stage a 32-code x 256-k tile (16 KB) into Cs[buf]; LDS dest linear
        // (gload_lds), XOR swizzle applied on the GLOBAL source.
        auto stageC = [&](int tile, int buf) {
#pragma unroll
            for (int it = 0; it < 2; ++it) {
                const int d   = (it * 512 + t) * 16;   // dest byte in 16KB buf
                const int row = d >> 9;                // 0..31
                const int kb  = d & 511;
                const int kbs = kb ^ ((row & 7) << 4);
                gload16(&Cb[(size_t)(tile * 32 + row) * 256 + (kbs >> 1)],
                        (char*)&Cs[buf][0] + d);
            }
        };

        stageC(0, 0);                     // overlap first staging with mirror
#pragma unroll
        for (int r = 0; r < 32; ++r) Rb[rh * 32 + r][col] = f2bf(R[r]);
        __syncthreads();

        // wave's 16 rows -> A fragments in registers for the whole stage
        bf16x8 a[8];
#pragma unroll
        for (int ks = 0; ks < 8; ++ks)
            a[ks] = *(const bf16x8*)&Rb[rg * 16 + lrow][ks * 32 + g * 8];

        float best[4]; int bidx[4];
#pragma unroll
        for (int j = 0; j < 4; ++j) { best[j] = 3.0e38f; bidx[j] = 0; }

        const int cr = cg * 16 + lrow;    // this lane's code row within tile

        int buf = 0;
#pragma unroll 1
        for (int tile = 0; tile < ntile; ++tile) {
            if (tile + 1 < ntile) stageC(tile + 1, buf ^ 1);
            const int   code = tile * 32 + cr;
            const float cn   = cns[code];
            f32x4 acc = (f32x4)0.f;
#pragma unroll
            for (int ks = 0; ks < 8; ++ks) {
                const int kb = (ks * 64 + g * 16) ^ ((cr & 7) << 4);
                bf16x8 b = *(const bf16x8*)((const char*)&Cs[buf][0]
                             + cr * 512 + kb);
                acc = mfma_bf16(a[ks], b, acc);
            }
#pragma unroll
            for (int j = 0; j < 4; ++j) {
                const float s = fmaf(-2.0f, acc[j], cn);
                if (s < best[j]) { best[j] = s; bidx[j] = code; }
            }
            __syncthreads();              // staging done + buf free
            buf ^= 1;
        }

        // argmin: 16 code-lanes within wave, then across the 2 code-halves
#pragma unroll
        for (int j = 0; j < 4; ++j) {
            float v = best[j]; int i = bidx[j];
#pragma unroll
            for (int d = 1; d < 16; d <<= 1) {
                const float ov = __shfl_xor(v, d);
                const int   oi = __shfl_xor(i, d);
                if (ov < v || (ov == v && oi < i)) { v = ov; i = oi; }
            }
            if (lrow == 0) {
                redv[rg * 16 + g * 4 + j][cg] = v;
                redi[rg * 16 + g * 4 + j][cg] = i;
            }
        }
        __syncthreads();
        if (t < 64) {
            float v = redv[t][0]; int i = redi[t][0];
            const float ov = redv[t][1]; const int oi = redi[t][1];
            if (ov < v || (ov == v && oi < i)) { v = ov; i = oi; }
            idxs[stage][t] = i;
        }
        __syncthreads();

        // residual update + commit loss (f32, thread owns its column)
        const float* Cfs = Cf[stage];
        float partial = 0.f;
#pragma unroll
        for (int r = 0; r < 32; ++r) {
            const float q  = Cfs[(size_t)idxs[stage][rh * 32 + r] * 256 + col];
            const float rn = R[r] - q;
            R[r] = rn;
            partial = fmaf(rn, rn, partial);
        }
#pragma unroll
        for (int d = 32; d; d >>= 1) partial += __shfl_down(partial, d);
        if (lane == 0) lred[wid] = partial;
        __syncthreads();
        if (t == 0) {
            float s = 0.f;
#pragma unroll
            for (int w2 = 0; w2 < 8; ++w2) s += lred[w2];
            atomicAdd(&lossOut[1 + stage], s * lscale);
        }
        __syncthreads();
    }

    // ZQ = q0 + q1 + q2 (f32 gather from L2-resident codebooks), bf16
#pragma unroll
    for (int r = 0; r < 32; ++r) {
        const int row = rh * 32 + r;
        const float zq = C0[(size_t)idxs[0][row] * 256 + col]
                       + C1[(size_t)idxs[1][row] * 256 + col]
                       + C2[(size_t)idxs[2][row] * 256 + col];
        ZQ[(size_t)(brow + row) * 256 + col] = f2bf(zq);
    }
}

// ---------------------------------------------------------------------------
extern "C" void kernel_launch(void* const* d_in, const int* in_sizes, int n_in,
                              void* d_out, int out_size, void* d_ws, size_t ws_size,
                              hipStream_t stream)
{
    const float* x   = (const float*)d_in[0];
    const float* eW1 = (const float*)d_in[1];
    const float* eb1 = (const float*)d_in[2];
    const float* eW2 = (const float*)d_in[3];
    const float* eb2 = (const float*)d_in[4];
    const float* dW1 = (const float*)d_in[5];
    const float* db1 = (const float*)d_in[6];
    const float* dW2 = (const float*)d_in[7];
    const float* db2 = (const float*)d_in[8];
    const float* C0  = (const float*)d_in[9];
    const float* C1  = (const float*)d_in[10];
    const float* C2  = (const float*)d_in[11];
    float* out = (float*)d_out;

    char* w = (char*)d_ws;
    u16*   H1   = (u16*)(w);                          // 64 MiB
    float* Zf   = (float*)(w + ((size_t)64 << 20));   // 64 MiB
    u16*   ZQ   = (u16*)(w + ((size_t)128 << 20));    // 32 MiB
    u16*   H2   = (u16*)(w + ((size_t)160 << 20));    // 64 MiB
    u16*   xbf  = (u16*)(w + ((size_t)230 << 20));    // 128 MiB
    u16*   eW1t = (u16*)(w + ((size_t)224 << 20));
    u16*   eW2t = (u16*)(w + ((size_t)225 << 20));
    u16*   dW1t = (u16*)(w + ((size_t)226 << 20));
    u16*   dW2t = (u16*)(w + ((size_t)227 << 20));
    u16*   Cbf  = (u16*)(w + ((size_t)228 << 20));
    float* cn   = (float*)(w + ((size_t)229 << 20));

    hipMemsetAsync(d_out, 0, 4 * sizeof(float), stream);

    prep_x<<<4096, 256, 0, stream>>>(x, xbf);
    prep_weights<<<5120, 256, 0, stream>>>(eW1, eW2, dW1, dW2, eW1t, eW2t, dW1t, dW2t);
    cb_prep<<<1792, 256, 0, stream>>>(C0, C1, C2, Cbf, cn);

    // G1: H1 = gelu(xbf @ eW1 + eb1)  M=65536 N=512 K=1024
    gemm_mfma<0><<<1024, 512, 0, stream>>>(
        xbf, eW1t, eb1, H1, nullptr, nullptr, nullptr, 512, 1024, 4, 0.f);
    // G2: Z = H1 @ eW2 + eb2          M=65536 N=256 K=512
    gemm_mfma<1><<<512, 512, 0, stream>>>(
        H1, eW2t, eb2, nullptr, Zf, nullptr, nullptr, 256, 512, 2, 0.f);
    // VQ: 3 stages, emits ZQ bf16 + losses[1..3]
    vq_mfma<<<1024, 512, 0, stream>>>(Zf, Cbf, cn, C0, C1, C2, ZQ, out);
    // G3: H2 = gelu(ZQ @ dW1 + db1)   M=65536 N=512 K=256
    gemm_mfma<0><<<1024, 512, 0, stream>>>(
        ZQ, dW1t, db1, H2, nullptr, nullptr, nullptr, 512, 256, 4, 0.f);
    // G4: recon loss                  M=65536 N=1024 K=512
    gemm_mfma<2><<<2048, 512, 0, stream>>>(
        H2, dW2t, db2, nullptr, nullptr, xbf, out, 1024, 512, 8,
        1.0f / (65536.0f * 1024.0f));
}

// Round 9
// 541.268 us; speedup vs baseline: 1.1078x; 1.1078x over previous
//
#include <hip/hip_runtime.h>
#include <cstddef>

// ---------------------------------------------------------------------------
// RQ-VAE forward, bf16-MFMA pipeline.
//   prep:  x -> bf16; weights -> Wt bf16 [N][K]; codebooks -> bf16 + norms
//   G1: H1 = gelu(xbf @ eW1 + eb1)                                    -> bf16
//   G2: Z  = H1 @ eW2 + eb2                                           -> f32
//   VQ: 3 stages (reg residual, LDS-staged swizzled codebook tiles)
//   G3: H2 = gelu(ZQ @ dW1 + db1)                                     -> bf16
//   G4: recon = mean((H2 @ dW2 + db2 - xbf)^2)   (loss-only epilogue)
// GEMM v3: m201-style 8-phase schedule. BM=256 BN=256 BK=64, 8 waves
// (2M x 4N), wave tile 128x64. LDS [2 dbuf][2 K-half] for A,B = 128 KB.
// Per K-tile: 4 phases {ds_read 4-8 b128 | stage 1 half-tile | vmcnt(8) |
// barrier | 16 MFMA setprio | barrier}. Stage slots lead reads by >=5
// phases; vmcnt(8) == allow 4 newest half-tiles (ledger-verified).
// ---------------------------------------------------------------------------

typedef __attribute__((ext_vector_type(8))) __bf16 bf16x8;
typedef __attribute__((ext_vector_type(4))) float f32x4;
typedef unsigned short u16;

__device__ __forceinline__ u16 f2bf(float f) {
    unsigned u = __float_as_uint(f);
    u += 0x7fffu + ((u >> 16) & 1u);      // round-to-nearest-even
    return (u16)(u >> 16);
}
__device__ __forceinline__ float bf2f(u16 b) {
    return __uint_as_float((unsigned)b << 16);
}
__device__ __forceinline__ float gelu_exact(float v) {
    return 0.5f * v * (1.0f + erff(v * 0.7071067811865475f));
}
__device__ __forceinline__ void gload16(const void* g, void* l) {
    __builtin_amdgcn_global_load_lds(
        (const __attribute__((address_space(1))) void*)g,
        (__attribute__((address_space(3))) void*)l, 16, 0, 0);
}
__device__ __forceinline__ f32x4 mfma_bf16(bf16x8 a, bf16x8 b, f32x4 c) {
    return __builtin_amdgcn_mfma_f32_16x16x32_bf16(a, b, c, 0, 0, 0);
}

// ---------------------------------------------------------------------------
// x -> bf16 (vectorized cast, grid-stride)
__global__ __launch_bounds__(256)
void prep_x(const float* __restrict__ x, u16* __restrict__ xbf)
{
    const size_t total = (size_t)65536 * 1024;
    const size_t step  = (size_t)gridDim.x * 256 * 8;
    for (size_t i = ((size_t)blockIdx.x * 256 + threadIdx.x) * 8; i < total; i += step) {
        float4 v0 = *(const float4*)&x[i];
        float4 v1 = *(const float4*)&x[i + 4];
        uint4 o;
        o.x = (unsigned)f2bf(v0.x) | ((unsigned)f2bf(v0.y) << 16);
        o.y = (unsigned)f2bf(v0.z) | ((unsigned)f2bf(v0.w) << 16);
        o.z = (unsigned)f2bf(v1.x) | ((unsigned)f2bf(v1.y) << 16);
        o.w = (unsigned)f2bf(v1.z) | ((unsigned)f2bf(v1.w) << 16);
        *(uint4*)&xbf[i] = o;
    }
}

// ---------------------------------------------------------------------------
// prep: transpose+cast the 4 weights to bf16 [N][K]
__global__ __launch_bounds__(256)
void prep_weights(const float* __restrict__ eW1, const float* __restrict__ eW2,
                  const float* __restrict__ dW1, const float* __restrict__ dW2,
                  u16* __restrict__ eW1t, u16* __restrict__ eW2t,
                  u16* __restrict__ dW1t, u16* __restrict__ dW2t)
{
    const int b = blockIdx.x, t = threadIdx.x;
    if (b < 2048) {                    // eW1 [1024][512] -> [512][1024]
        int e = b * 256 + t;
        int n = e >> 10, k = e & 1023;
        eW1t[e] = f2bf(eW1[(size_t)k * 512 + n]);
    } else if (b < 2560) {             // eW2 [512][256] -> [256][512]
        int e = (b - 2048) * 256 + t;
        int n = e >> 9, k = e & 511;
        eW2t[e] = f2bf(eW2[(size_t)k * 256 + n]);
    } else if (b < 3072) {             // dW1 [256][512] -> [512][256]
        int e = (b - 2560) * 256 + t;
        int n = e >> 8, k = e & 255;
        dW1t[e] = f2bf(dW1[(size_t)k * 512 + n]);
    } else {                           // dW2 [512][1024] -> [1024][512]
        int e = (b - 3072) * 256 + t;
        int n = e >> 9, k = e & 511;
        dW2t[e] = f2bf(dW2[(size_t)k * 1024 + n]);
    }
}

// codebooks: bf16 cast (contiguous [1792][256]) + f32 squared norms
__global__ __launch_bounds__(256)
void cb_prep(const float* __restrict__ C0, const float* __restrict__ C1,
             const float* __restrict__ C2, u16* __restrict__ Cbf,
             float* __restrict__ cnorm)
{
    __shared__ float red[256];
    const int code = blockIdx.x, t = threadIdx.x;
    const float* C;
    int local;
    if (code < 1024)      { C = C0; local = code; }
    else if (code < 1536) { C = C1; local = code - 1024; }
    else                  { C = C2; local = code - 1536; }
    const float v = C[(size_t)local * 256 + t];
    Cbf[(size_t)code * 256 + t] = f2bf(v);
    red[t] = v * v;
    __syncthreads();
    for (int s = 128; s; s >>= 1) { if (t < s) red[t] += red[t + s]; __syncthreads(); }
    if (t == 0) cnorm[code] = red[0];
}

// ---------------------------------------------------------------------------
// MFMA GEMM v3 (8-phase). See header comment.
// EPI: 0 = gelu -> bf16 store, 1 = plain -> f32 store, 2 = sq-err loss vs Xbf
template <int EPI>
__global__ __launch_bounds__(512, 2)
void gemm_mfma(const u16* __restrict__ A, const u16* __restrict__ Bt,
               const float* __restrict__ bias, u16* __restrict__ Obf,
               float* __restrict__ Of, const u16* __restrict__ Xbf,
               float* __restrict__ lossOut, int N, int K, int ntn,
               float lossScale)
{
    // [dbuf][kh][256 rows x 32 k] each; 64 KB per operand, 128 KB total
    __shared__ __align__(16) u16 SA[2][2][8192];
    __shared__ __align__(16) u16 SB[2][2][8192];

    const int nwg = gridDim.x;
    const int bid = blockIdx.x;
    const int wg  = (bid & 7) * (nwg >> 3) + (bid >> 3);   // XCD-chunked swizzle
    const int brow = (wg / ntn) * 256;
    const int bcol = (wg % ntn) * 256;

    const int t    = threadIdx.x;
    const int lane = t & 63;
    const int wid  = t >> 6;
    const int wrow = (wid >> 2) * 128;   // 2 M-groups of 128
    const int wcol = (wid & 3) * 64;     // 4 N-groups of 64
    const int lrow = lane & 15, g = lane >> 4;

    const int nt = K >> 6;   // K-tiles of 64

    f32x4 acc[8][4];
#pragma unroll
    for (int m = 0; m < 8; ++m)
#pragma unroll
        for (int n = 0; n < 4; ++n) acc[m][n] = (f32x4)0.f;

    // stage one 16 KB half-tile (rows x 32 k) into `region`.
    // 64B LDS rows; source chunk pre-swizzled by c ^= (R>>1)&3.
    auto stage_half = [&](const u16* __restrict__ src, int row0, int Ts,
                          int kh, char* region) {
#pragma unroll
        for (int it = 0; it < 2; ++it) {
            const int d  = (it * 512 + t) * 16;
            const int R  = d >> 6;
            const int cs = ((d >> 4) & 3) ^ ((R >> 1) & 3);
            gload16(&src[(size_t)(row0 + R) * K + Ts * 64 + kh * 32 + cs * 8],
                    region + d);
        }
    };

    // prologue: T0 all 4 halves + T1 kh0 (6 half-tiles = 12 loads)
    stage_half(A,  brow, 0, 0, (char*)&SA[0][0][0]);
    stage_half(Bt, bcol, 0, 0, (char*)&SB[0][0][0]);
    stage_half(A,  brow, 0, 1, (char*)&SA[0][1][0]);
    stage_half(Bt, bcol, 0, 1, (char*)&SB[0][1][0]);
    stage_half(A,  brow, 1, 0, (char*)&SA[1][0][0]);
    stage_half(Bt, bcol, 1, 0, (char*)&SB[1][0][0]);
    asm volatile("s_waitcnt vmcnt(8)" ::: "memory");   // T0.kh0 landed
    __builtin_amdgcn_s_barrier();

    bf16x8 bfr[4];   // B frags live across the 2 phases of a kk

#define PHASE(MH, KK, DO_B, STAGE_CODE)                                        \
    {                                                                          \
        bf16x8 a_[4];                                                          \
        _Pragma("unroll")                                                      \
        for (int mi = 0; mi < 4; ++mi) {                                       \
            const int R = wrow + ((MH) * 4 + mi) * 16 + lrow;                  \
            a_[mi] = *(const bf16x8*)((const char*)&SA[d][KK][0]               \
                      + R * 64 + ((g ^ ((R >> 1) & 3)) << 4));                 \
        }                                                                      \
        if (DO_B) {                                                            \
            _Pragma("unroll")                                                  \
            for (int n = 0; n < 4; ++n) {                                      \
                const int R = wcol + n * 16 + lrow;                            \
                bfr[n] = *(const bf16x8*)((const char*)&SB[d][KK][0]           \
                          + R * 64 + ((g ^ ((R >> 1) & 3)) << 4));             \
            }                                                                  \
        }                                                                      \
        STAGE_CODE;                                                            \
        if (T >= nt - 2) asm volatile("s_waitcnt vmcnt(0)" ::: "memory");      \
        else             asm volatile("s_waitcnt vmcnt(8)" ::: "memory");      \
        __builtin_amdgcn_s_barrier();                                          \
        __builtin_amdgcn_s_setprio(1);                                         \
        _Pragma("unroll")                                                      \
        for (int mi = 0; mi < 4; ++mi)                                         \
            _Pragma("unroll")                                                  \
            for (int n = 0; n < 4; ++n)                                        \
                acc[(MH) * 4 + mi][n] =                                        \
                    mfma_bf16(a_[mi], bfr[n], acc[(MH) * 4 + mi][n]);          \
        __builtin_amdgcn_s_setprio(0);                                         \
        __builtin_amdgcn_s_barrier();                                          \
    }

    for (int T = 0; T < nt; ++T) {
        const int d = T & 1;
        // p1: mh0 kk0 | stage (T+1).kh1.A
        PHASE(0, 0, 1,
              if (T + 1 < nt) stage_half(A, brow, T + 1, 1,
                                         (char*)&SA[(T + 1) & 1][1][0]));
        // p2: mh1 kk0 | stage (T+1).kh1.B
        PHASE(1, 0, 0,
              if (T + 1 < nt) stage_half(Bt, bcol, T + 1, 1,
                                         (char*)&SB[(T + 1) & 1][1][0]));
        // p3: mh0 kk1 | stage (T+2).kh0.A
        PHASE(0, 1, 1,
              if (T + 2 < nt) stage_half(A, brow, T + 2, 0,
                                         (char*)&SA[T & 1][0][0]));
        // p4: mh1 kk1 | stage (T+2).kh0.B
        PHASE(1, 1, 0,
              if (T + 2 < nt) stage_half(Bt, bcol, T + 2, 0,
                                         (char*)&SB[T & 1][0][0]));
    }
#undef PHASE

    // ---- epilogue ----
    int   colN[4];
    float bn[4];
#pragma unroll
    for (int n = 0; n < 4; ++n) {
        colN[n] = bcol + wcol + n * 16 + lrow;
        bn[n]   = bias[colN[n]];
    }

    if (EPI == 0) {
#pragma unroll
        for (int m = 0; m < 8; ++m) {
            const int rowb = brow + wrow + m * 16 + (lane >> 4) * 4;
#pragma unroll
            for (int n = 0; n < 4; ++n)
#pragma unroll
                for (int j = 0; j < 4; ++j)
                    Obf[(size_t)(rowb + j) * N + colN[n]] =
                        f2bf(gelu_exact(acc[m][n][j] + bn[n]));
        }
    } else if (EPI == 1) {
#pragma unroll
        for (int m = 0; m < 8; ++m) {
            const int rowb = brow + wrow + m * 16 + (lane >> 4) * 4;
#pragma unroll
            for (int n = 0; n < 4; ++n)
#pragma unroll
                for (int j = 0; j < 4; ++j)
                    Of[(size_t)(rowb + j) * N + colN[n]] = acc[m][n][j] + bn[n];
        }
    } else {
        float partial = 0.f;
#pragma unroll
        for (int m = 0; m < 8; ++m) {
            const int rowb = brow + wrow + m * 16 + (lane >> 4) * 4;
#pragma unroll
            for (int n = 0; n < 4; ++n)
#pragma unroll
                for (int j = 0; j < 4; ++j) {
                    const float o = acc[m][n][j] + bn[n];
                    const float d = o - bf2f(Xbf[(size_t)(rowb + j) * N + colN[n]]);
                    partial = fmaf(d, d, partial);
                }
        }
        __syncthreads();                 // all waves out of the K-loop (LDS reuse)
        float* red = (float*)&SA[0][0][0];
        red[t] = partial;
        __syncthreads();
        for (int s = 256; s; s >>= 1) { if (t < s) red[t] += red[t + s]; __syncthreads(); }
        if (t == 0) atomicAdd(lossOut, red[0] * lossScale);
    }
}

// ---------------------------------------------------------------------------
// VQ v5 (unchanged from r8): 512 threads, 64 rows/block.
__global__ __launch_bounds__(512, 4)
void vq_mfma(const float* __restrict__ Z, const u16* __restrict__ Cbf,
             const float* __restrict__ cnorm,
             const float* __restrict__ C0, const float* __restrict__ C1,
             const float* __restrict__ C2,
             u16* __restrict__ ZQ, float* __restrict__ lossOut)
{
    __shared__ __align__(16) u16 Rb[64][264];      // 33.8 KB residual mirror
    __shared__ __align__(16) u16 Cs[2][32 * 256];  // 2 x 16 KB code tiles
    __shared__ float redv[64][2];
    __shared__ int   redi[64][2];
    __shared__ int   idxs[3][64];
    __shared__ float lred[8];

    const int t    = threadIdx.x;
    const int lane = t & 63;
    const int wid  = t >> 6;           // 0..7
    const int rg   = wid & 3;          // row group (16 rows)
    const int cg   = wid >> 2;         // code half
    const int lrow = lane & 15, g = lane >> 4;
    const int col  = t & 255;          // owned column
    const int rh   = t >> 8;           // row half (32 rows)
    const int brow = blockIdx.x * 64;

    float R[32];
#pragma unroll
    for (int r = 0; r < 32; ++r)
        R[r] = Z[(size_t)(brow + rh * 32 + r) * 256 + col];

    const float* Cf[3]  = {C0, C1, C2};
    const int ncodes[3] = {1024, 512, 256};
    const int coff[3]   = {0, 1024, 1536};
    const float lscale  = 1.25f / (65536.0f * 256.0f);

    for (int stage = 0; stage < 3; ++stage) {
        const u16*   Cb  = Cbf + (size_t)coff[stage] * 256;
        const float* cns = cnorm + coff[stage];
        const int ntile  = ncodes[stage] >> 5;

        auto stageC = [&](int tile, int buf) {
#pragma unroll
            for (int it = 0; it < 2; ++it) {
                const int d   = (it * 512 + t) * 16;   // dest byte in 16KB buf
                const int row = d >> 9;                // 0..31
                const int kb  = d & 511;
                const int kbs = kb ^ ((row & 7) << 4);
                gload16(&Cb[(size_t)(tile * 32 + row) * 256 + (kbs >> 1)],
                        (char*)&Cs[buf][0] + d);
            }
        };

        stageC(0, 0);                     // overlap first staging with mirror
#pragma unroll
        for (int r = 0; r < 32; ++r) Rb[rh * 32 + r][col] = f2bf(R[r]);
        __syncthreads();

        bf16x8 a[8];
#pragma unroll
        for (int ks = 0; ks < 8; ++ks)
            a[ks] = *(const bf16x8*)&Rb[rg * 16 + lrow][ks * 32 + g * 8];

        float best[4]; int bidx[4];
#pragma unroll
        for (int j = 0; j < 4; ++j) { best[j] = 3.0e38f; bidx[j] = 0; }

        const int cr = cg * 16 + lrow;    // this lane's code row within tile

        int buf = 0;
#pragma unroll 1
        for (int tile = 0; tile < ntile; ++tile) {
            if (tile + 1 < ntile) stageC(tile + 1, buf ^ 1);
            const int   code = tile * 32 + cr;
            const float cn   = cns[code];
            f32x4 acc = (f32x4)0.f;
#pragma unroll
            for (int ks = 0; ks < 8; ++ks) {
                const int kb = (ks * 64 + g * 16) ^ ((cr & 7) << 4);
                bf16x8 b = *(const bf16x8*)((const char*)&Cs[buf][0]
                             + cr * 512 + kb);
                acc = mfma_bf16(a[ks], b, acc);
            }
#pragma unroll
            for (int j = 0; j < 4; ++j) {
                const float s = fmaf(-2.0f, acc[j], cn);
                if (s < best[j]) { best[j] = s; bidx[j] = code; }
            }
            __syncthreads();              // staging done + buf free
            buf ^= 1;
        }

        // argmin: 16 code-lanes within wave, then across the 2 code-halves
#pragma unroll
        for (int j = 0; j < 4; ++j) {
            float v = best[j]; int i = bidx[j];
#pragma unroll
            for (int d = 1; d < 16; d <<= 1) {
                const float ov = __shfl_xor(v, d);
                const int   oi = __shfl_xor(i, d);
                if (ov < v || (ov == v && oi < i)) { v = ov; i = oi; }
            }
            if (lrow == 0) {
                redv[rg * 16 + g * 4 + j][cg] = v;
                redi[rg * 16 + g * 4 + j][cg] = i;
            }
        }
        __syncthreads();
        if (t < 64) {
            float v = redv[t][0]; int i = redi[t][0];
            const float ov = redv[t][1]; const int oi = redi[t][1];
            if (ov < v || (ov == v && oi < i)) { v = ov; i = oi; }
            idxs[stage][t] = i;
        }
        __syncthreads();

        // residual update + commit loss (f32, thread owns its column)
        const float* Cfs = Cf[stage];
        float partial = 0.f;
#pragma unroll
        for (int r = 0; r < 32; ++r) {
            const float q  = Cfs[(size_t)idxs[stage][rh * 32 + r] * 256 + col];
            const float rn = R[r] - q;
            R[r] = rn;
            partial = fmaf(rn, rn, partial);
        }
#pragma unroll
        for (int d = 32; d; d >>= 1) partial += __shfl_down(partial, d);
        if (lane == 0) lred[wid] = partial;
        __syncthreads();
        if (t == 0) {
            float s = 0.f;
#pragma unroll
            for (int w2 = 0; w2 < 8; ++w2) s += lred[w2];
            atomicAdd(&lossOut[1 + stage], s * lscale);
        }
        __syncthreads();
    }

    // ZQ = q0 + q1 + q2 (f32 gather from L2-resident codebooks), bf16
#pragma unroll
    for (int r = 0; r < 32; ++r) {
        const int row = rh * 32 + r;
        const float zq = C0[(size_t)idxs[0][row] * 256 + col]
                       + C1[(size_t)idxs[1][row] * 256 + col]
                       + C2[(size_t)idxs[2][row] * 256 + col];
        ZQ[(size_t)(brow + row) * 256 + col] = f2bf(zq);
    }
}

// ---------------------------------------------------------------------------
extern "C" void kernel_launch(void* const* d_in, const int* in_sizes, int n_in,
                              void* d_out, int out_size, void* d_ws, size_t ws_size,
                              hipStream_t stream)
{
    const float* x   = (const float*)d_in[0];
    const float* eW1 = (const float*)d_in[1];
    const float* eb1 = (const float*)d_in[2];
    const float* eW2 = (const float*)d_in[3];
    const float* eb2 = (const float*)d_in[4];
    const float* dW1 = (const float*)d_in[5];
    const float* db1 = (const float*)d_in[6];
    const float* dW2 = (const float*)d_in[7];
    const float* db2 = (const float*)d_in[8];
    const float* C0  = (const float*)d_in[9];
    const float* C1  = (const float*)d_in[10];
    const float* C2  = (const float*)d_in[11];
    float* out = (float*)d_out;

    char* w = (char*)d_ws;
    u16*   H1   = (u16*)(w);                          // 64 MiB
    float* Zf   = (float*)(w + ((size_t)64 << 20));   // 64 MiB
    u16*   ZQ   = (u16*)(w + ((size_t)128 << 20));    // 32 MiB
    u16*   H2   = (u16*)(w + ((size_t)160 << 20));    // 64 MiB
    u16*   xbf  = (u16*)(w + ((size_t)230 << 20));    // 128 MiB
    u16*   eW1t = (u16*)(w + ((size_t)224 << 20));
    u16*   eW2t = (u16*)(w + ((size_t)225 << 20));
    u16*   dW1t = (u16*)(w + ((size_t)226 << 20));
    u16*   dW2t = (u16*)(w + ((size_t)227 << 20));
    u16*   Cbf  = (u16*)(w + ((size_t)228 << 20));
    float* cn   = (float*)(w + ((size_t)229 << 20));

    hipMemsetAsync(d_out, 0, 4 * sizeof(float), stream);

    prep_x<<<4096, 256, 0, stream>>>(x, xbf);
    prep_weights<<<5120, 256, 0, stream>>>(eW1, eW2, dW1, dW2, eW1t, eW2t, dW1t, dW2t);
    cb_prep<<<1792, 256, 0, stream>>>(C0, C1, C2, Cbf, cn);

    // G1: H1 = gelu(xbf @ eW1 + eb1)  M=65536 N=512 K=1024   (256 x 2 tiles)
    gemm_mfma<0><<<512, 512, 0, stream>>>(
        xbf, eW1t, eb1, H1, nullptr, nullptr, nullptr, 512, 1024, 2, 0.f);
    // G2: Z = H1 @ eW2 + eb2          M=65536 N=256 K=512    (256 x 1)
    gemm_mfma<1><<<256, 512, 0, stream>>>(
        H1, eW2t, eb2, nullptr, Zf, nullptr, nullptr, 256, 512, 1, 0.f);
    // VQ: 3 stages, emits ZQ bf16 + losses[1..3]
    vq_mfma<<<1024, 512, 0, stream>>>(Zf, Cbf, cn, C0, C1, C2, ZQ, out);
    // G3: H2 = gelu(ZQ @ dW1 + db1)   M=65536 N=512 K=256    (256 x 2)
    gemm_mfma<0><<<512, 512, 0, stream>>>(
        ZQ, dW1t, db1, H2, nullptr, nullptr, nullptr, 512, 256, 2, 0.f);
    // G4: recon loss                  M=65536 N=1024 K=512   (256 x 4)
    gemm_mfma<2><<<1024, 512, 0, stream>>>(
        H2, dW2t, db2, nullptr, nullptr, xbf, out, 1024, 512, 4,
        1.0f / (65536.0f * 1024.0f));
}